// Round 3
// baseline (801.099 us; speedup 1.0000x reference)
//
#include <hip/hip_runtime.h>
#include <hip/hip_bf16.h>

#define N_NODES 50000
#define N_EDGES 600000
#define N_GRAPHS 64
#define HID 128
#define NLAYERS 4
#define IN_DIM 5
#define NCLS 5
#define EPS 1e-5f
#define SCAN_BLK ((N_NODES + 511) / 512)   // 98
#define POOL_CHUNKS 16
#define BSLOT 64  // BN-stat atomic slots (per layer)
#define WS 136    // bf16 LDS row stride (MFMA kernel)
#define NT_BUILD (SCAN_BLK * 512)          // 50176 threads in build kernel
#define LGRID 768                          // 3 blocks/CU x 256 CU (cooperative)
#define LGRID_FB 512                       // fallback: 2 blocks/CU guaranteed

typedef __attribute__((ext_vector_type(8))) short s16x8;
typedef __attribute__((ext_vector_type(4))) float f32x4;

// bf16 helpers (RNE)
__device__ __forceinline__ unsigned short f2bf(float x) {
    unsigned u = __float_as_uint(x);
    unsigned r = (u + 0x7fffu + ((u >> 16) & 1u)) >> 16;
    return (unsigned short)r;
}
__device__ __forceinline__ float2 bfpair(unsigned u) {
    float2 r;
    r.x = __uint_as_float(u << 16);
    r.y = __uint_as_float(u & 0xffff0000u);
    return r;
}
__device__ __forceinline__ float bf2f(unsigned short s) {
    return __uint_as_float(((unsigned)s) << 16);
}

// ---- device-scope grid barrier (sense-reversing, state in workspace) ----
// release fence -> arrive -> spin relaxed (s_sleep backoff) -> acquire fence.
// Safe iff all gridDim.x blocks co-resident (cooperative launch guarantees;
// fallback grids sized for guaranteed residency: LDS/threads/VGPR checked).
__device__ __forceinline__ void gridbar(int* cnt, int* gen, int nblk) {
    __syncthreads();
    if (threadIdx.x == 0) {
        int g = __hip_atomic_load(gen, __ATOMIC_RELAXED, __HIP_MEMORY_SCOPE_AGENT);
        __threadfence();  // release our phase's writes
        int a = __hip_atomic_fetch_add(cnt, 1, __ATOMIC_RELAXED, __HIP_MEMORY_SCOPE_AGENT);
        if (a == nblk - 1) {
            __hip_atomic_store(cnt, 0, __ATOMIC_RELAXED, __HIP_MEMORY_SCOPE_AGENT);
            __hip_atomic_store(gen, g + 1, __ATOMIC_RELEASE, __HIP_MEMORY_SCOPE_AGENT);
        } else {
            while (__hip_atomic_load(gen, __ATOMIC_RELAXED, __HIP_MEMORY_SCOPE_AGENT) == g)
                __builtin_amdgcn_s_sleep(2);
        }
        __threadfence();  // acquire remote phase's writes
    }
    __syncthreads();
}

// ---------------- fused CSR build: zero+count+scan+fill+Wt, 1 dispatch ----------------

__global__ __launch_bounds__(512) void k_build(const int* __restrict__ src,
                                               const int* __restrict__ dst,
                                               const int* __restrict__ batch,
                                               const float* __restrict__ Wg,
                                               int* __restrict__ counts,
                                               int* __restrict__ cursor,
                                               float* __restrict__ psum,
                                               float* __restrict__ psq,
                                               int* __restrict__ rp,
                                               int* __restrict__ bsum,
                                               int2* __restrict__ cw,
                                               float* __restrict__ dinv,
                                               int* __restrict__ gstart,
                                               unsigned short* __restrict__ WtG,
                                               int* bcnt, int* bgen) {
    __shared__ int s[512];
    int t = threadIdx.x;
    int b = blockIdx.x;
    int gtid = b * 512 + t;
    // P0: zero scratch consumed by atomics below
    for (int i = gtid; i < N_NODES; i += NT_BUILD) { counts[i] = 0; cursor[i] = 0; }
    for (int i = gtid; i < NLAYERS * BSLOT * HID; i += NT_BUILD) { psum[i] = 0.f; psq[i] = 0.f; }
    gridbar(bcnt, bgen, SCAN_BLK);
    // P1: degree count
    for (int e = gtid; e < N_EDGES; e += NT_BUILD) atomicAdd(&counts[dst[e]], 1);
    gridbar(bcnt, bgen, SCAN_BLK);
    // P2: block-local inclusive scan of this block's 512 counts
    {
        int v = (gtid < N_NODES) ? counts[gtid] : 0;
        s[t] = v;
        __syncthreads();
        for (int off = 1; off < 512; off <<= 1) {
            int x = (t >= off) ? s[t - off] : 0;
            __syncthreads();
            s[t] += x;
            __syncthreads();
        }
        if (gtid < N_NODES) rp[gtid + 1] = s[t];
        if (t == 511) bsum[b] = s[511];
    }
    gridbar(bcnt, bgen, SCAN_BLK);
    // P3: block 0 scans the block partials; block 1 finds graph starts
    if (b == 0) {
        int v = (t < SCAN_BLK) ? bsum[t] : 0;
        s[t] = v;
        __syncthreads();
        for (int off = 1; off < 128; off <<= 1) {
            int x = (t >= off) ? s[t - off] : 0;
            __syncthreads();
            s[t] += x;
            __syncthreads();
        }
        if (t < SCAN_BLK) bsum[t] = s[t] - v;  // exclusive
    } else if (b == 1) {
        if (t <= N_GRAPHS) {
            int lo = 0, hi = N_NODES;
            while (lo < hi) {
                int mid = (lo + hi) >> 1;
                if (batch[mid] < t) lo = mid + 1; else hi = mid;
            }
            gstart[t] = lo;
        }
    }
    gridbar(bcnt, bgen, SCAN_BLK);
    // P4: rp fixup + dinv
    if (gtid < N_NODES) {
        rp[gtid + 1] += bsum[b];
        dinv[gtid] = rsqrtf((float)(counts[gtid] + 1));
    }
    if (gtid == 0) rp[0] = 0;
    gridbar(bcnt, bgen, SCAN_BLK);
    // P5: fill packed (col,w) pairs + W transpose->bf16
    for (int e = gtid; e < N_EDGES; e += NT_BUILD) {
        int d = dst[e];
        int pos = atomicAdd(&cursor[d], 1);
        int sn = src[e];
        int2 p;
        p.x = sn;
        p.y = __float_as_int(dinv[sn]);
        cw[rp[d] + pos] = p;
    }
    for (int idx = gtid; idx < NLAYERS * HID * HID; idx += NT_BUILD) {
        int l = idx >> 14;
        int r = idx & 16383;
        int n = r >> 7, k = r & 127;
        WtG[idx] = f2bf(Wg[l * HID * HID + k * HID + n]);
    }
}

// ---------------- fused layer pipeline: 4x(GEMM, gather) + pool + head ----------------
// Phase bodies identical to the previous separate kernels; phases separated by
// gridbar. LDS = 53248 B -> exactly 3 blocks/CU; grid 768 co-resident via
// cooperative launch. Gather/pool/head reuse the gemm LDS via casts.

__global__ __launch_bounds__(256, 3) void k_layers(const float* __restrict__ x,
                                                   const float* __restrict__ Wp,
                                                   const float* __restrict__ bp,
                                                   const unsigned short* __restrict__ WtG,
                                                   const float* __restrict__ bgA,
                                                   const float* __restrict__ gammaA,
                                                   const float* __restrict__ betaA,
                                                   const int* __restrict__ rp,
                                                   const int2* __restrict__ cw,
                                                   const float* __restrict__ dinv,
                                                   const int* __restrict__ gstart,
                                                   unsigned short* __restrict__ A,
                                                   unsigned short* __restrict__ B,
                                                   float* __restrict__ psumA,
                                                   float* __restrict__ psqA,
                                                   const float* __restrict__ W1,
                                                   const float* __restrict__ b1,
                                                   const float* __restrict__ W2,
                                                   const float* __restrict__ b2,
                                                   const float* __restrict__ W3,
                                                   const float* __restrict__ b3,
                                                   float* __restrict__ out,
                                                   float* __restrict__ poolPart,
                                                   int* bcnt, int* bgen) {
    __shared__ unsigned short Wt[HID * WS];   // 34816 B
    __shared__ unsigned short Al[64 * WS];    // 17408 B
    __shared__ float scl[HID], shf[HID];      // 1024 B  -> total 53248 B
    int t = threadIdx.x;
    int nblk = gridDim.x;
    int lane = t & 63, wv = t >> 6;

    for (int l = 0; l < NLAYERS; l++) {
        // ---- GEMM phase: B = act(in) @ Wg[l] ----
        const unsigned short* Wl = WtG + (size_t)l * HID * HID;
        int pl = (l == 0) ? 0 : (l - 1);
        const float* psum = psumA + (size_t)pl * BSLOT * HID;
        const float* psq = psqA + (size_t)pl * BSLOT * HID;
        {
            const uint4* Wg4 = (const uint4*)Wl;
            for (int idx = t; idx < HID * 16; idx += 256) {
                int n = idx >> 4, c = idx & 15;
                *(uint4*)&Wt[n * WS + c * 8] = Wg4[idx];
            }
        }
        if (l > 0 && t < HID) {
            float s = 0.f, s2 = 0.f;
#pragma unroll 8
            for (int bb = 0; bb < BSLOT; bb++) {
                s += psum[bb * HID + t];
                s2 += psq[bb * HID + t];
            }
            const float invN = 1.f / (float)N_NODES;
            float mu = s * invN;
            float var = s2 * invN - mu * mu;
            float rs = rsqrtf(var + EPS) * gammaA[pl * HID + t];
            scl[t] = rs;
            shf[t] = betaA[pl * HID + t] - mu * rs;
        }
        int rbase = (wv & 1) * 32;
        int cbase = (wv >> 1) * 64;
        int mr = lane & 15, q = lane >> 4;
        const int numTiles = (N_NODES + 63) / 64;
        for (int tile = blockIdx.x; tile < numTiles; tile += nblk) {
            int n0 = tile * 64;
            int limRow = min(64, N_NODES - n0);
            __syncthreads();  // orders Wt/scl writes (1st iter) + Al reuse
            if (l == 0) {
                for (int idx = t; idx < 64 * HID; idx += 256) {
                    int n = idx >> 7, k = idx & 127;
                    int node = n0 + n;
                    float acc = 0.f;
                    if (node < N_NODES) {
                        acc = bp[k];
#pragma unroll
                        for (int j = 0; j < IN_DIM; j++) acc += x[node * IN_DIM + j] * Wp[j * HID + k];
                    }
                    Al[n * WS + k] = f2bf(acc);
                }
            } else {
                const uint2* Ag = (const uint2*)(A + (size_t)n0 * HID);
                for (int idx = t; idx < 64 * 32; idx += 256) {
                    int row = idx >> 5, c4 = idx & 31;
                    uint2 u = (row < limRow) ? Ag[row * 32 + c4] : make_uint2(0u, 0u);
                    float2 ab = bfpair(u.x);
                    float2 cd = bfpair(u.y);
                    int kf = c4 * 4;
                    float4 sc = *(const float4*)&scl[kf];
                    float4 sh = *(const float4*)&shf[kf];
                    float v0 = fmaxf(ab.x * sc.x + sh.x, 0.f);
                    float v1 = fmaxf(ab.y * sc.y + sh.y, 0.f);
                    float v2 = fmaxf(cd.x * sc.z + sh.z, 0.f);
                    float v3 = fmaxf(cd.y * sc.w + sh.w, 0.f);
                    unsigned lo = (unsigned)f2bf(v0) | ((unsigned)f2bf(v1) << 16);
                    unsigned hi = (unsigned)f2bf(v2) | ((unsigned)f2bf(v3) << 16);
                    *(uint2*)&Al[row * WS + kf] = make_uint2(lo, hi);
                }
            }
            __syncthreads();
            f32x4 acc[2][4];
#pragma unroll
            for (int rt = 0; rt < 2; rt++)
#pragma unroll
                for (int ct = 0; ct < 4; ct++) acc[rt][ct] = (f32x4){0.f, 0.f, 0.f, 0.f};
#pragma unroll
            for (int kk = 0; kk < HID; kk += 32) {
                s16x8 a0 = *(const s16x8*)&Al[(rbase + mr) * WS + kk + q * 8];
                s16x8 a1 = *(const s16x8*)&Al[(rbase + 16 + mr) * WS + kk + q * 8];
#pragma unroll
                for (int ct = 0; ct < 4; ct++) {
                    s16x8 bfr = *(const s16x8*)&Wt[(cbase + ct * 16 + mr) * WS + kk + q * 8];
                    acc[0][ct] = __builtin_amdgcn_mfma_f32_16x16x32_bf16(a0, bfr, acc[0][ct], 0, 0, 0);
                    acc[1][ct] = __builtin_amdgcn_mfma_f32_16x16x32_bf16(a1, bfr, acc[1][ct], 0, 0, 0);
                }
            }
            __syncthreads();
#pragma unroll
            for (int rt = 0; rt < 2; rt++)
#pragma unroll
                for (int ct = 0; ct < 4; ct++)
#pragma unroll
                    for (int r = 0; r < 4; r++) {
                        int rloc = rbase + rt * 16 + q * 4 + r;
                        int f = cbase + ct * 16 + mr;
                        Al[rloc * WS + f] = f2bf(acc[rt][ct][r]);
                    }
            __syncthreads();
            for (int idx = t; idx < 64 * 16; idx += 256) {
                int row = idx >> 4, c = idx & 15;
                if (row < limRow)
                    *(uint4*)&B[(size_t)(n0 + row) * HID + c * 8] = *(const uint4*)&Al[row * WS + c * 8];
            }
        }
        gridbar(bcnt, bgen, nblk);

        // ---- gather phase: A = D^-1/2 (adj+I) D^-1/2 B + bg[l], BN stats ----
        {
            const uint4* Bm4 = (const uint4*)B;
            float* ls = (float*)Wt;          // 2 KB scratch inside Wt region
            float* lq = ls + 4 * HID;
            const float* bgl = bgA + l * HID;
            float* psumW = psumA + (size_t)l * BSLOT * HID;
            float* psqW = psqA + (size_t)l * BSLOT * HID;
            int sfc = lane & 15;   // 16B feature chunk
            int p = lane >> 4;     // node slot 0..3
            int f = sfc * 8;
            for (int u = blockIdx.x; u < N_NODES / 16; u += nblk) {
                int v = u * 16 + wv * 4 + p;
                int beg = rp[v], end = rp[v + 1];
                float dv = dinv[v];
                float a0, a1, a2, a3, a4, a5, a6, a7;
                {
                    uint4 uu = Bm4[(size_t)v * 16 + sfc];
                    float2 q0 = bfpair(uu.x), q1 = bfpair(uu.y), q2 = bfpair(uu.z), q3 = bfpair(uu.w);
                    a0 = q0.x * dv; a1 = q0.y * dv; a2 = q1.x * dv; a3 = q1.y * dv;
                    a4 = q2.x * dv; a5 = q2.y * dv; a6 = q3.x * dv; a7 = q3.y * dv;
                }
                int e = beg;
                for (; e + 1 < end; e += 2) {
                    int2 pe0 = cw[e];
                    int2 pe1 = cw[e + 1];
                    uint4 u0 = Bm4[(size_t)pe0.x * 16 + sfc];
                    uint4 u1 = Bm4[(size_t)pe1.x * 16 + sfc];
                    float w0 = __int_as_float(pe0.y);
                    float w1 = __int_as_float(pe1.y);
                    float2 x0 = bfpair(u0.x), x1 = bfpair(u0.y), x2 = bfpair(u0.z), x3 = bfpair(u0.w);
                    float2 y0 = bfpair(u1.x), y1 = bfpair(u1.y), y2 = bfpair(u1.z), y3 = bfpair(u1.w);
                    a0 += x0.x * w0 + y0.x * w1;
                    a1 += x0.y * w0 + y0.y * w1;
                    a2 += x1.x * w0 + y1.x * w1;
                    a3 += x1.y * w0 + y1.y * w1;
                    a4 += x2.x * w0 + y2.x * w1;
                    a5 += x2.y * w0 + y2.y * w1;
                    a6 += x3.x * w0 + y3.x * w1;
                    a7 += x3.y * w0 + y3.y * w1;
                }
                if (e < end) {
                    int2 pe = cw[e];
                    uint4 uu = Bm4[(size_t)pe.x * 16 + sfc];
                    float w = __int_as_float(pe.y);
                    float2 x0 = bfpair(uu.x), x1 = bfpair(uu.y), x2 = bfpair(uu.z), x3 = bfpair(uu.w);
                    a0 += x0.x * w; a1 += x0.y * w; a2 += x1.x * w; a3 += x1.y * w;
                    a4 += x2.x * w; a5 += x2.y * w; a6 += x3.x * w; a7 += x3.y * w;
                }
                float r0 = a0 * dv + bgl[f + 0];
                float r1 = a1 * dv + bgl[f + 1];
                float r2 = a2 * dv + bgl[f + 2];
                float r3 = a3 * dv + bgl[f + 3];
                float r4 = a4 * dv + bgl[f + 4];
                float r5 = a5 * dv + bgl[f + 5];
                float r6 = a6 * dv + bgl[f + 6];
                float r7 = a7 * dv + bgl[f + 7];
                unsigned short c0 = f2bf(r0), c1 = f2bf(r1), c2 = f2bf(r2), c3 = f2bf(r3);
                unsigned short c4 = f2bf(r4), c5 = f2bf(r5), c6 = f2bf(r6), c7 = f2bf(r7);
                uint4 o;
                o.x = (unsigned)c0 | ((unsigned)c1 << 16);
                o.y = (unsigned)c2 | ((unsigned)c3 << 16);
                o.z = (unsigned)c4 | ((unsigned)c5 << 16);
                o.w = (unsigned)c6 | ((unsigned)c7 << 16);
                *(uint4*)&A[(size_t)v * HID + f] = o;
                float v0 = bf2f(c0), v1 = bf2f(c1), v2 = bf2f(c2), v3 = bf2f(c3);
                float v4 = bf2f(c4), v5 = bf2f(c5), v6 = bf2f(c6), v7 = bf2f(c7);
                float ts0 = v0, ts1 = v1, ts2 = v2, ts3 = v3;
                float ts4 = v4, ts5 = v5, ts6 = v6, ts7 = v7;
                float tq0 = v0 * v0, tq1 = v1 * v1, tq2 = v2 * v2, tq3 = v3 * v3;
                float tq4 = v4 * v4, tq5 = v5 * v5, tq6 = v6 * v6, tq7 = v7 * v7;
                ts0 += __shfl_xor(ts0, 16); ts1 += __shfl_xor(ts1, 16);
                ts2 += __shfl_xor(ts2, 16); ts3 += __shfl_xor(ts3, 16);
                ts4 += __shfl_xor(ts4, 16); ts5 += __shfl_xor(ts5, 16);
                ts6 += __shfl_xor(ts6, 16); ts7 += __shfl_xor(ts7, 16);
                tq0 += __shfl_xor(tq0, 16); tq1 += __shfl_xor(tq1, 16);
                tq2 += __shfl_xor(tq2, 16); tq3 += __shfl_xor(tq3, 16);
                tq4 += __shfl_xor(tq4, 16); tq5 += __shfl_xor(tq5, 16);
                tq6 += __shfl_xor(tq6, 16); tq7 += __shfl_xor(tq7, 16);
                ts0 += __shfl_xor(ts0, 32); ts1 += __shfl_xor(ts1, 32);
                ts2 += __shfl_xor(ts2, 32); ts3 += __shfl_xor(ts3, 32);
                ts4 += __shfl_xor(ts4, 32); ts5 += __shfl_xor(ts5, 32);
                ts6 += __shfl_xor(ts6, 32); ts7 += __shfl_xor(ts7, 32);
                tq0 += __shfl_xor(tq0, 32); tq1 += __shfl_xor(tq1, 32);
                tq2 += __shfl_xor(tq2, 32); tq3 += __shfl_xor(tq3, 32);
                tq4 += __shfl_xor(tq4, 32); tq5 += __shfl_xor(tq5, 32);
                tq6 += __shfl_xor(tq6, 32); tq7 += __shfl_xor(tq7, 32);
                if (p == 0) {
                    float* lsw = &ls[wv * HID + f];
                    float* lqw = &lq[wv * HID + f];
                    lsw[0] = ts0; lsw[1] = ts1; lsw[2] = ts2; lsw[3] = ts3;
                    lsw[4] = ts4; lsw[5] = ts5; lsw[6] = ts6; lsw[7] = ts7;
                    lqw[0] = tq0; lqw[1] = tq1; lqw[2] = tq2; lqw[3] = tq3;
                    lqw[4] = tq4; lqw[5] = tq5; lqw[6] = tq6; lqw[7] = tq7;
                }
                __syncthreads();
                if (t < HID) {
                    float ssum = ls[t] + ls[HID + t] + ls[2 * HID + t] + ls[3 * HID + t];
                    float ssq = lq[t] + lq[HID + t] + lq[2 * HID + t] + lq[3 * HID + t];
                    int slot = u & (BSLOT - 1);
                    atomicAdd(&psumW[slot * HID + t], ssum);
                    atomicAdd(&psqW[slot * HID + t], ssq);
                }
                __syncthreads();  // ls/lq reuse next unit
            }
        }
        gridbar(bcnt, bgen, nblk);
    }

    // ---- pool phase (layer-3 BN derived in-phase) ----
    {
        const float* psum3 = psumA + (size_t)3 * BSLOT * HID;
        const float* psq3 = psqA + (size_t)3 * BSLOT * HID;
        int half = t >> 7;
        int f = t & 127;
        for (int u = blockIdx.x * 2 + half; u < N_GRAPHS * POOL_CHUNKS; u += nblk * 2) {
            int g = u >> 4, c = u & (POOL_CHUNKS - 1);
            float s = 0.f, s2 = 0.f;
#pragma unroll 8
            for (int bb = 0; bb < BSLOT; bb++) {
                s += psum3[bb * HID + f];
                s2 += psq3[bb * HID + f];
            }
            const float invN = 1.f / (float)N_NODES;
            float mu = s * invN;
            float var = s2 * invN - mu * mu;
            float sc = rsqrtf(var + EPS) * gammaA[3 * HID + f];
            float sh = betaA[3 * HID + f] - mu * sc;
            int beg = gstart[g], end = gstart[g + 1];
            int len = end - beg;
            int per = (len + POOL_CHUNKS - 1) / POOL_CHUNKS;
            int s0 = beg + c * per;
            int s1 = min(s0 + per, end);
            float sa = 0.f, sb = 0.f, ma = 0.f, mb = 0.f;
            int n = s0;
            for (; n + 1 < s1; n += 2) {
                float v0 = bf2f(A[(size_t)n * HID + f]);
                float v1 = bf2f(A[(size_t)(n + 1) * HID + f]);
                v0 = fmaxf(v0 * sc + sh, 0.f);
                v1 = fmaxf(v1 * sc + sh, 0.f);
                sa += v0; ma = fmaxf(ma, v0);
                sb += v1; mb = fmaxf(mb, v1);
            }
            if (n < s1) {
                float v = fmaxf(bf2f(A[(size_t)n * HID + f]) * sc + sh, 0.f);
                sa += v; ma = fmaxf(ma, v);
            }
            poolPart[((size_t)g * POOL_CHUNKS + c) * 256 + f] = sa + sb;
            poolPart[((size_t)g * POOL_CHUNKS + c) * 256 + 128 + f] = fmaxf(ma, mb);
        }
    }
    gridbar(bcnt, bgen, nblk);

    // ---- head phase (blocks 0..63; all 256 threads hit the syncs) ----
    if (blockIdx.x < N_GRAPHS) {
        float* plm = (float*)Al;
        float* h1 = plm + 2 * HID;
        float* h2 = h1 + HID;
        int g = blockIdx.x;
        float gcnt = fmaxf((float)(gstart[g + 1] - gstart[g]), 1.f);
        if (t < 128) {
            float s = 0.f, mx = 0.f;
#pragma unroll
            for (int c = 0; c < POOL_CHUNKS; c++) {
                const float* pp = &poolPart[((size_t)g * POOL_CHUNKS + c) * 256];
                s += pp[t];
                mx = fmaxf(mx, pp[128 + t]);
            }
            plm[t] = s / gcnt;
            plm[HID + t] = mx;
        }
        __syncthreads();
        if (t < 128) {
            float acc = b1[t];
            for (int k = 0; k < 2 * HID; k++) acc += plm[k] * W1[k * HID + t];
            h1[t] = fmaxf(acc, 0.f);
        }
        __syncthreads();
        if (t < HID / 2) {
            float a2 = b2[t];
            for (int k = 0; k < HID; k++) a2 += h1[k] * W2[k * (HID / 2) + t];
            h2[t] = fmaxf(a2, 0.f);
        }
        __syncthreads();
        if (t < NCLS) {
            float a3 = b3[t];
            for (int k = 0; k < HID / 2; k++) a3 += h2[k] * W3[k * NCLS + t];
            out[g * NCLS + t] = a3;
        }
    }
}

extern "C" void kernel_launch(void* const* d_in, const int* in_sizes, int n_in,
                              void* d_out, int out_size, void* d_ws, size_t ws_size,
                              hipStream_t stream) {
    const float* x     = (const float*)d_in[0];
    const int*   ei    = (const int*)d_in[1];
    const int*   batch = (const int*)d_in[2];
    const float* Wp    = (const float*)d_in[3];
    const float* bp    = (const float*)d_in[4];
    const float* Wg    = (const float*)d_in[5];
    const float* bg    = (const float*)d_in[6];
    const float* gamma = (const float*)d_in[7];
    const float* beta  = (const float*)d_in[8];
    const float* W1    = (const float*)d_in[9];
    const float* b1    = (const float*)d_in[10];
    const float* W2    = (const float*)d_in[11];
    const float* b2    = (const float*)d_in[12];
    const float* W3    = (const float*)d_in[13];
    const float* b3    = (const float*)d_in[14];
    const int* src = ei;
    const int* dst = ei + N_EDGES;
    float* out = (float*)d_out;

    char* base = (char*)d_ws;
    size_t off = 0;
    auto alloc = [&](size_t bytes) -> void* {
        void* p = base + off;
        off += (bytes + 255) & ~(size_t)255;
        return p;
    };
    // zeroed region: barrier state only (counts/cursor/psum/psq zeroed in-kernel)
    int* bcnt = (int*)alloc(4);
    int* bgen = (int*)alloc(4);
    size_t zeroBytes = off;  // 512
    int*   counts = (int*)alloc((size_t)N_NODES * 4);
    int*   cursor = (int*)alloc((size_t)N_NODES * 4);
    float* psum   = (float*)alloc((size_t)NLAYERS * BSLOT * HID * 4);
    float* psq    = (float*)alloc((size_t)NLAYERS * BSLOT * HID * 4);
    int*   rp      = (int*)alloc((size_t)(N_NODES + 1) * 4);
    int*   bsum    = (int*)alloc(128 * 4);
    int2*  cw      = (int2*)alloc((size_t)N_EDGES * 8);
    float* dinv    = (float*)alloc((size_t)N_NODES * 4);
    int*   gstart  = (int*)alloc((size_t)(N_GRAPHS + 1) * 4);
    float* poolPart= (float*)alloc((size_t)N_GRAPHS * POOL_CHUNKS * 256 * 4);
    unsigned short* WtG = (unsigned short*)alloc((size_t)NLAYERS * HID * HID * 2);
    unsigned short* A = (unsigned short*)alloc((size_t)N_NODES * HID * 2);
    unsigned short* B = (unsigned short*)alloc((size_t)N_NODES * HID * 2);
    (void)ws_size; (void)in_sizes; (void)n_in; (void)out_size;

    hipMemsetAsync(d_ws, 0, zeroBytes, stream);

    {
        void* bargs[] = { (void*)&src, (void*)&dst, (void*)&batch, (void*)&Wg,
                          (void*)&counts, (void*)&cursor, (void*)&psum, (void*)&psq,
                          (void*)&rp, (void*)&bsum, (void*)&cw, (void*)&dinv,
                          (void*)&gstart, (void*)&WtG, (void*)&bcnt, (void*)&bgen };
        if (hipLaunchCooperativeKernel((void*)k_build, dim3(SCAN_BLK), dim3(512),
                                       bargs, 0, stream) != hipSuccess) {
            k_build<<<SCAN_BLK, 512, 0, stream>>>(src, dst, batch, Wg, counts, cursor,
                                                  psum, psq, rp, bsum, cw, dinv, gstart,
                                                  WtG, bcnt, bgen);
        }
    }
    {
        void* largs[] = { (void*)&x, (void*)&Wp, (void*)&bp, (void*)&WtG, (void*)&bg,
                          (void*)&gamma, (void*)&beta, (void*)&rp, (void*)&cw,
                          (void*)&dinv, (void*)&gstart, (void*)&A, (void*)&B,
                          (void*)&psum, (void*)&psq, (void*)&W1, (void*)&b1,
                          (void*)&W2, (void*)&b2, (void*)&W3, (void*)&b3,
                          (void*)&out, (void*)&poolPart, (void*)&bcnt, (void*)&bgen };
        if (hipLaunchCooperativeKernel((void*)k_layers, dim3(LGRID), dim3(256),
                                       largs, 0, stream) != hipSuccess) {
            // fallback: smaller grid with guaranteed co-residency (2 blocks/CU)
            k_layers<<<LGRID_FB, 256, 0, stream>>>(x, Wp, bp, WtG, bg, gamma, beta, rp,
                                                   cw, dinv, gstart, A, B, psum, psq,
                                                   W1, b1, W2, b2, W3, b3, out, poolPart,
                                                   bcnt, bgen);
        }
    }
}

// Round 4
// 412.520 us; speedup vs baseline: 1.9420x; 1.9420x over previous
//
#include <hip/hip_runtime.h>
#include <hip/hip_bf16.h>

#define N_NODES 50000
#define N_EDGES 600000
#define N_GRAPHS 64
#define HID 128
#define NLAYERS 4
#define IN_DIM 5
#define NCLS 5
#define EPS 1e-5f
#define SCAN_BLK ((N_NODES + 511) / 512)
#define FILL_BLK ((N_EDGES + 255) / 256)
#define POOL_CHUNKS 16
#define BSLOT 64  // BN-stat atomic slots (per layer)
#define WS 136    // bf16 LDS row stride (MFMA kernel)

typedef __attribute__((ext_vector_type(8))) short s16x8;
typedef __attribute__((ext_vector_type(4))) float f32x4;

// bf16 helpers (RNE)
__device__ __forceinline__ unsigned short f2bf(float x) {
    unsigned u = __float_as_uint(x);
    unsigned r = (u + 0x7fffu + ((u >> 16) & 1u)) >> 16;
    return (unsigned short)r;
}
__device__ __forceinline__ float2 bfpair(unsigned u) {
    float2 r;
    r.x = __uint_as_float(u << 16);
    r.y = __uint_as_float(u & 0xffff0000u);
    return r;
}
__device__ __forceinline__ float bf2f(unsigned short s) {
    return __uint_as_float(((unsigned)s) << 16);
}

// ---------------- CSR build ----------------

__global__ void k_count(const int* __restrict__ dst, int* __restrict__ cnt) {
    int i = blockIdx.x * blockDim.x + threadIdx.x;
    if (i < N_EDGES) atomicAdd(&cnt[dst[i]], 1);
}

__global__ void k_scan1(const int* __restrict__ cnt, int* __restrict__ rp, int* __restrict__ bsum) {
    __shared__ int s[512];
    int t = threadIdx.x;
    int i = blockIdx.x * 512 + t;
    int v = (i < N_NODES) ? cnt[i] : 0;
    s[t] = v;
    __syncthreads();
    for (int off = 1; off < 512; off <<= 1) {
        int x = (t >= off) ? s[t - off] : 0;
        __syncthreads();
        s[t] += x;
        __syncthreads();
    }
    if (i < N_NODES) rp[i + 1] = s[t];
    if (t == 511) bsum[blockIdx.x] = s[511];
}

__global__ void k_scan2g(int* __restrict__ bsum, const int* __restrict__ batch,
                         int* __restrict__ gstart) {
    if (blockIdx.x == 0) {
        __shared__ int s[128];
        int t = threadIdx.x;
        int v = (t < SCAN_BLK) ? bsum[t] : 0;
        s[t] = v;
        __syncthreads();
        for (int off = 1; off < 128; off <<= 1) {
            int x = (t >= off) ? s[t - off] : 0;
            __syncthreads();
            s[t] += x;
            __syncthreads();
        }
        if (t < SCAN_BLK) bsum[t] = s[t] - v;
    } else {
        int t = threadIdx.x;
        if (t <= N_GRAPHS) {
            int lo = 0, hi = N_NODES;
            while (lo < hi) {
                int mid = (lo + hi) >> 1;
                if (batch[mid] < t) lo = mid + 1; else hi = mid;
            }
            gstart[t] = lo;
        }
    }
}

__global__ void k_scan3d(int* __restrict__ rp, const int* __restrict__ bsum,
                         const int* __restrict__ cnt, float* __restrict__ dinv) {
    int i = blockIdx.x * 512 + threadIdx.x;
    if (i < N_NODES) {
        rp[i + 1] += bsum[blockIdx.x];
        dinv[i] = rsqrtf((float)(cnt[i] + 1));
    }
    if (i == 0) rp[0] = 0;
}

// fill packed (col, w) pairs; trailing blocks do the W transpose+bf16 convert
__global__ void k_fillw(const int* __restrict__ src, const int* __restrict__ dst,
                        const int* __restrict__ rp, int* __restrict__ cursor,
                        int2* __restrict__ cw, const float* __restrict__ dinv,
                        const float* __restrict__ Wg, unsigned short* __restrict__ WtG) {
    int b = blockIdx.x;
    if (b < FILL_BLK) {
        int e = b * 256 + threadIdx.x;
        if (e < N_EDGES) {
            int d = dst[e];
            int pos = atomicAdd(&cursor[d], 1);
            int s = src[e];
            int2 p;
            p.x = s;
            p.y = __float_as_int(dinv[s]);
            cw[rp[d] + pos] = p;
        }
    } else {
        int idx = (b - FILL_BLK) * 256 + threadIdx.x;  // < NLAYERS*HID*HID
        int l = idx >> 14;
        int r = idx & 16383;
        int n = r >> 7, k = r & 127;
        WtG[idx] = f2bf(Wg[l * HID * HID + k * HID + n]);
    }
}

// ---------------- GEMM (MFMA): Bm(bf16) = act(in) @ W ----------------
// layer0: in = x @ Wp + bp (x/Wp/bp read direct from global; L1-resident,
// broadcast within wave -> no LDS staging needed). Else: in = relu(A*sc+sh),
// sc/sh derived in-kernel from the previous gather's psum/psq slots.
// W comes pre-transposed+bf16 (WtG[n][k]) -> coalesced uint4 + ds_write_b128.
// LDS 53248 B (Wt+Al+scl/shf) -> 3 blocks/CU; grid 768 = 256 CU x 3.
// Epilogue bounces acc through Al -> coalesced uint4 global stores.

__global__ __launch_bounds__(256, 3) void k_gemmM(const unsigned short* __restrict__ Abf,
                                                  const float* __restrict__ x,
                                                  const float* __restrict__ Wp,
                                                  const float* __restrict__ bp,
                                                  const unsigned short* __restrict__ WtG,
                                                  unsigned short* __restrict__ Bm,
                                                  const float* __restrict__ psum,
                                                  const float* __restrict__ psq,
                                                  const float* __restrict__ gamma,
                                                  const float* __restrict__ beta,
                                                  int layer0) {
    __shared__ unsigned short Wt[HID * WS];
    __shared__ unsigned short Al[64 * WS];
    __shared__ float scl[HID], shf[HID];
    int t = threadIdx.x;
    {
        const uint4* Wg4 = (const uint4*)WtG;
        for (int idx = t; idx < HID * 16; idx += 256) {
            int n = idx >> 4, c = idx & 15;
            *(uint4*)&Wt[n * WS + c * 8] = Wg4[idx];
        }
    }
    if (!layer0 && t < HID) {
        float s = 0.f, s2 = 0.f;
#pragma unroll 8
        for (int b = 0; b < BSLOT; b++) {
            s += psum[b * HID + t];
            s2 += psq[b * HID + t];
        }
        const float invN = 1.f / (float)N_NODES;
        float mu = s * invN;
        float var = s2 * invN - mu * mu;
        float rs = rsqrtf(var + EPS) * gamma[t];
        scl[t] = rs;
        shf[t] = beta[t] - mu * rs;
    }
    int lane = t & 63, wv = t >> 6;
    int rbase = (wv & 1) * 32;
    int cbase = (wv >> 1) * 64;
    int mr = lane & 15, q = lane >> 4;
    const int numTiles = (N_NODES + 63) / 64;
    for (int tile = blockIdx.x; tile < numTiles; tile += gridDim.x) {
        int n0 = tile * 64;
        int limRow = min(64, N_NODES - n0);
        __syncthreads();  // orders scl/Wt writes (1st iter) + Al reuse safety
        if (layer0) {
            for (int idx = t; idx < 64 * HID; idx += 256) {
                int n = idx >> 7, k = idx & 127;
                int node = n0 + n;
                float acc = 0.f;
                if (node < N_NODES) {
                    acc = bp[k];
#pragma unroll
                    for (int j = 0; j < IN_DIM; j++) acc += x[node * IN_DIM + j] * Wp[j * HID + k];
                }
                Al[n * WS + k] = f2bf(acc);
            }
        } else {
            const uint2* Ag = (const uint2*)(Abf + (size_t)n0 * HID);
            for (int idx = t; idx < 64 * 32; idx += 256) {
                int row = idx >> 5, c4 = idx & 31;
                uint2 u = (row < limRow) ? Ag[row * 32 + c4] : make_uint2(0u, 0u);
                float2 ab = bfpair(u.x);
                float2 cd = bfpair(u.y);
                int kf = c4 * 4;
                float4 sc = *(const float4*)&scl[kf];
                float4 sh = *(const float4*)&shf[kf];
                float v0 = fmaxf(ab.x * sc.x + sh.x, 0.f);
                float v1 = fmaxf(ab.y * sc.y + sh.y, 0.f);
                float v2 = fmaxf(cd.x * sc.z + sh.z, 0.f);
                float v3 = fmaxf(cd.y * sc.w + sh.w, 0.f);
                unsigned lo = (unsigned)f2bf(v0) | ((unsigned)f2bf(v1) << 16);
                unsigned hi = (unsigned)f2bf(v2) | ((unsigned)f2bf(v3) << 16);
                *(uint2*)&Al[row * WS + kf] = make_uint2(lo, hi);
            }
        }
        __syncthreads();
        f32x4 acc[2][4];
#pragma unroll
        for (int rt = 0; rt < 2; rt++)
#pragma unroll
            for (int ct = 0; ct < 4; ct++) acc[rt][ct] = (f32x4){0.f, 0.f, 0.f, 0.f};
#pragma unroll
        for (int kk = 0; kk < HID; kk += 32) {
            s16x8 a0 = *(const s16x8*)&Al[(rbase + mr) * WS + kk + q * 8];
            s16x8 a1 = *(const s16x8*)&Al[(rbase + 16 + mr) * WS + kk + q * 8];
#pragma unroll
            for (int ct = 0; ct < 4; ct++) {
                s16x8 b = *(const s16x8*)&Wt[(cbase + ct * 16 + mr) * WS + kk + q * 8];
                acc[0][ct] = __builtin_amdgcn_mfma_f32_16x16x32_bf16(a0, b, acc[0][ct], 0, 0, 0);
                acc[1][ct] = __builtin_amdgcn_mfma_f32_16x16x32_bf16(a1, b, acc[1][ct], 0, 0, 0);
            }
        }
        __syncthreads();  // all waves done reading Al fragments
        // stage C tile into Al (bf16), then coalesced uint4 global stores
#pragma unroll
        for (int rt = 0; rt < 2; rt++)
#pragma unroll
            for (int ct = 0; ct < 4; ct++)
#pragma unroll
                for (int r = 0; r < 4; r++) {
                    int rloc = rbase + rt * 16 + q * 4 + r;
                    int f = cbase + ct * 16 + mr;
                    Al[rloc * WS + f] = f2bf(acc[rt][ct][r]);
                }
        __syncthreads();
        for (int idx = t; idx < 64 * 16; idx += 256) {
            int row = idx >> 4, c = idx & 15;
            if (row < limRow)
                *(uint4*)&Bm[(size_t)(n0 + row) * HID + c * 8] = *(const uint4*)&Al[row * WS + c * 8];
        }
    }
}

// ---------------- CSR gather + fused BN partial stats ----------------
// R4 restructure: ONE NODE PER WAVE. 64 lanes x 4B (2 bf16 feats/lane) = one
// 256B row per load instruction; loop bounds wave-uniform (scalar branch, no
// divergence-masked iterations, no max-over-groups waste). cw entries fetched
// 4-at-a-time as 16B-aligned uniform loads (peel one edge if beg is odd);
// 4 rows in flight per wave. Per-lane state ~2 floats -> low VGPR -> high
// occupancy for latency hiding. BN stats: 4 regs/lane across the wave's
// nodes, one LDS float2-reduce + 256 atomics per block at the end.

__global__ __launch_bounds__(256) void k_gather(const unsigned* __restrict__ Bm2,
                                                const int* __restrict__ rp,
                                                const int2* __restrict__ cw,
                                                const float* __restrict__ dinv,
                                                const float* __restrict__ bg,
                                                unsigned* __restrict__ Aout2,
                                                float* __restrict__ psum,
                                                float* __restrict__ psq) {
    __shared__ float ls[4 * HID], lq[4 * HID];
    int wv = threadIdx.x >> 6, lane = threadIdx.x & 63;
    const int totalWaves = gridDim.x * 4;
    int gw = blockIdx.x * 4 + wv;
    float bg0 = bg[2 * lane], bg1 = bg[2 * lane + 1];
    float ts0 = 0.f, ts1 = 0.f, tq0 = 0.f, tq1 = 0.f;
    for (int v = gw; v < N_NODES; v += totalWaves) {
        int beg = rp[v], end = rp[v + 1];
        float dv = dinv[v];
        float ax, ay;
        {
            float2 sl = bfpair(Bm2[(size_t)v * 64 + lane]);
            ax = sl.x * dv;
            ay = sl.y * dv;
        }
        int e = beg;
        if ((e & 1) && e < end) {  // peel to even e so int4 loads are 16B-aligned
            int2 c = cw[e];
            float2 f = bfpair(Bm2[(size_t)c.x * 64 + lane]);
            float w = __int_as_float(c.y);
            ax += f.x * w;
            ay += f.y * w;
            e++;
        }
        for (; e + 3 < end; e += 4) {
            int4 c01 = *(const int4*)&cw[e];       // cw[e], cw[e+1]
            int4 c23 = *(const int4*)&cw[e + 2];   // cw[e+2], cw[e+3]
            unsigned r0 = Bm2[(size_t)c01.x * 64 + lane];
            unsigned r1 = Bm2[(size_t)c01.z * 64 + lane];
            unsigned r2 = Bm2[(size_t)c23.x * 64 + lane];
            unsigned r3 = Bm2[(size_t)c23.z * 64 + lane];
            float w0 = __int_as_float(c01.y), w1 = __int_as_float(c01.w);
            float w2 = __int_as_float(c23.y), w3 = __int_as_float(c23.w);
            float2 f0 = bfpair(r0), f1 = bfpair(r1);
            float2 f2 = bfpair(r2), f3 = bfpair(r3);
            ax += f0.x * w0 + f1.x * w1 + f2.x * w2 + f3.x * w3;
            ay += f0.y * w0 + f1.y * w1 + f2.y * w2 + f3.y * w3;
        }
        for (; e < end; e++) {
            int2 c = cw[e];
            float2 f = bfpair(Bm2[(size_t)c.x * 64 + lane]);
            float w = __int_as_float(c.y);
            ax += f.x * w;
            ay += f.y * w;
        }
        float r0 = ax * dv + bg0, r1 = ay * dv + bg1;
        unsigned short h0 = f2bf(r0), h1 = f2bf(r1);
        Aout2[(size_t)v * 64 + lane] = (unsigned)h0 | ((unsigned)h1 << 16);
        // BN stats on the bf16-rounded values (what the next GEMM sees)
        float v0 = bf2f(h0), v1 = bf2f(h1);
        ts0 += v0; ts1 += v1;
        tq0 += v0 * v0; tq1 += v1 * v1;
    }
    *(float2*)&ls[wv * HID + 2 * lane] = make_float2(ts0, ts1);
    *(float2*)&lq[wv * HID + 2 * lane] = make_float2(tq0, tq1);
    __syncthreads();
    int t = threadIdx.x;
    if (t < HID) {
        float ssum = ls[t] + ls[HID + t] + ls[2 * HID + t] + ls[3 * HID + t];
        float ssq = lq[t] + lq[HID + t] + lq[2 * HID + t] + lq[3 * HID + t];
        int slot = blockIdx.x & (BSLOT - 1);
        atomicAdd(&psum[slot * HID + t], ssum);
        atomicAdd(&psq[slot * HID + t], ssq);
    }
}

// ---------------- segmented pooling, chunked; derives layer-3 BN in-kernel ----------------

__global__ __launch_bounds__(128) void k_pool(const unsigned short* __restrict__ A,
                                              const float* __restrict__ psum,
                                              const float* __restrict__ psq,
                                              const float* __restrict__ gamma,
                                              const float* __restrict__ beta,
                                              const int* __restrict__ gstart,
                                              float* __restrict__ poolPart) {
    int g = blockIdx.x;
    int c = blockIdx.y;
    int f = threadIdx.x;
    float s = 0.f, s2 = 0.f;
#pragma unroll 8
    for (int b = 0; b < BSLOT; b++) {
        s += psum[b * HID + f];
        s2 += psq[b * HID + f];
    }
    const float invN = 1.f / (float)N_NODES;
    float mu = s * invN;
    float var = s2 * invN - mu * mu;
    float sc = rsqrtf(var + EPS) * gamma[f];
    float sh = beta[f] - mu * sc;
    int beg = gstart[g], end = gstart[g + 1];
    int len = end - beg;
    int per = (len + POOL_CHUNKS - 1) / POOL_CHUNKS;
    int s0 = beg + c * per;
    int s1 = min(s0 + per, end);
    float sa = 0.f, sb = 0.f, ma = 0.f, mb = 0.f;
    int n = s0;
    for (; n + 1 < s1; n += 2) {
        float v0 = bf2f(A[(size_t)n * HID + f]);
        float v1 = bf2f(A[(size_t)(n + 1) * HID + f]);
        v0 = fmaxf(v0 * sc + sh, 0.f);
        v1 = fmaxf(v1 * sc + sh, 0.f);
        sa += v0; ma = fmaxf(ma, v0);
        sb += v1; mb = fmaxf(mb, v1);
    }
    if (n < s1) {
        float v = fmaxf(bf2f(A[(size_t)n * HID + f]) * sc + sh, 0.f);
        sa += v; ma = fmaxf(ma, v);
    }
    poolPart[((size_t)g * POOL_CHUNKS + c) * 256 + f] = sa + sb;
    poolPart[((size_t)g * POOL_CHUNKS + c) * 256 + 128 + f] = fmaxf(ma, mb);
}

// ---------------- MLP head ----------------

__global__ __launch_bounds__(128) void k_head(const float* __restrict__ poolPart,
                                              const int* __restrict__ gstart,
                                              const float* __restrict__ W1, const float* __restrict__ b1,
                                              const float* __restrict__ W2, const float* __restrict__ b2,
                                              const float* __restrict__ W3, const float* __restrict__ b3,
                                              float* __restrict__ out) {
    __shared__ float pl[2 * HID];
    __shared__ float h1[HID];
    __shared__ float h2[HID / 2];
    int g = blockIdx.x, t = threadIdx.x;
    float cnt = fmaxf((float)(gstart[g + 1] - gstart[g]), 1.f);
    float s = 0.f, mx = 0.f;
#pragma unroll
    for (int c = 0; c < POOL_CHUNKS; c++) {
        const float* p = &poolPart[((size_t)g * POOL_CHUNKS + c) * 256];
        s += p[t];
        mx = fmaxf(mx, p[128 + t]);
    }
    pl[t] = s / cnt;
    pl[HID + t] = mx;
    __syncthreads();
    float acc = b1[t];
    for (int k = 0; k < 2 * HID; k++) acc += pl[k] * W1[k * HID + t];
    h1[t] = fmaxf(acc, 0.f);
    __syncthreads();
    if (t < HID / 2) {
        float a2 = b2[t];
        for (int k = 0; k < HID; k++) a2 += h1[k] * W2[k * (HID / 2) + t];
        h2[t] = fmaxf(a2, 0.f);
    }
    __syncthreads();
    if (t < NCLS) {
        float a3 = b3[t];
        for (int k = 0; k < HID / 2; k++) a3 += h2[k] * W3[k * NCLS + t];
        out[g * NCLS + t] = a3;
    }
}

extern "C" void kernel_launch(void* const* d_in, const int* in_sizes, int n_in,
                              void* d_out, int out_size, void* d_ws, size_t ws_size,
                              hipStream_t stream) {
    const float* x     = (const float*)d_in[0];
    const int*   ei    = (const int*)d_in[1];
    const int*   batch = (const int*)d_in[2];
    const float* Wp    = (const float*)d_in[3];
    const float* bp    = (const float*)d_in[4];
    const float* Wg    = (const float*)d_in[5];
    const float* bg    = (const float*)d_in[6];
    const float* gamma = (const float*)d_in[7];
    const float* beta  = (const float*)d_in[8];
    const float* W1    = (const float*)d_in[9];
    const float* b1    = (const float*)d_in[10];
    const float* W2    = (const float*)d_in[11];
    const float* b2    = (const float*)d_in[12];
    const float* W3    = (const float*)d_in[13];
    const float* b3    = (const float*)d_in[14];
    const int* src = ei;
    const int* dst = ei + N_EDGES;
    float* out = (float*)d_out;

    char* base = (char*)d_ws;
    size_t off = 0;
    auto alloc = [&](size_t bytes) -> void* {
        void* p = base + off;
        off += (bytes + 255) & ~(size_t)255;
        return p;
    };
    // zeroed region (one memset)
    int*   counts = (int*)alloc((size_t)N_NODES * 4);
    int*   cursor = (int*)alloc((size_t)N_NODES * 4);
    float* psum   = (float*)alloc((size_t)NLAYERS * BSLOT * HID * 4);
    float* psq    = (float*)alloc((size_t)NLAYERS * BSLOT * HID * 4);
    size_t zeroBytes = off;
    // non-zeroed scratch
    int*   rp      = (int*)alloc((size_t)(N_NODES + 1) * 4);
    int*   bsum    = (int*)alloc(128 * 4);
    int2*  cw      = (int2*)alloc((size_t)N_EDGES * 8);
    float* dinv    = (float*)alloc((size_t)N_NODES * 4);
    int*   gstart  = (int*)alloc((size_t)(N_GRAPHS + 1) * 4);
    float* poolPart= (float*)alloc((size_t)N_GRAPHS * POOL_CHUNKS * 256 * 4);
    unsigned short* WtG = (unsigned short*)alloc((size_t)NLAYERS * HID * HID * 2);
    unsigned short* A = (unsigned short*)alloc((size_t)N_NODES * HID * 2);
    unsigned short* B = (unsigned short*)alloc((size_t)N_NODES * HID * 2);
    (void)ws_size; (void)in_sizes; (void)n_in; (void)out_size;

    hipMemsetAsync(d_ws, 0, zeroBytes, stream);

    k_count<<<(N_EDGES + 255) / 256, 256, 0, stream>>>(dst, counts);
    k_scan1<<<SCAN_BLK, 512, 0, stream>>>(counts, rp, bsum);
    k_scan2g<<<2, 128, 0, stream>>>(bsum, batch, gstart);
    k_scan3d<<<SCAN_BLK, 512, 0, stream>>>(rp, bsum, counts, dinv);
    k_fillw<<<FILL_BLK + (NLAYERS * HID * HID) / 256, 256, 0, stream>>>(
        src, dst, rp, cursor, cw, dinv, Wg, WtG);

    for (int i = 0; i < NLAYERS; i++) {
        int pl = (i == 0) ? 0 : (i - 1);
        k_gemmM<<<768, 256, 0, stream>>>(A, x, Wp, bp, WtG + (size_t)i * HID * HID, B,
                                         psum + (size_t)pl * BSLOT * HID,
                                         psq + (size_t)pl * BSLOT * HID,
                                         gamma + pl * HID, beta + pl * HID,
                                         (i == 0) ? 1 : 0);
        k_gather<<<N_NODES / 16, 256, 0, stream>>>((const unsigned*)B, rp, cw, dinv,
                                                   bg + i * HID, (unsigned*)A,
                                                   psum + (size_t)i * BSLOT * HID,
                                                   psq + (size_t)i * BSLOT * HID);
    }
    dim3 pg(N_GRAPHS, POOL_CHUNKS);
    k_pool<<<pg, 128, 0, stream>>>(A, psum + (size_t)3 * BSLOT * HID,
                                   psq + (size_t)3 * BSLOT * HID,
                                   gamma + 3 * HID, beta + 3 * HID, gstart, poolPart);
    k_head<<<N_GRAPHS, 128, 0, stream>>>(poolPart, gstart, W1, b1, W2, b2, W3, b3, out);
}